// Round 10
// baseline (170.875 us; speedup 1.0000x reference)
//
#include <hip/hip_runtime.h>

typedef _Float16 half8 __attribute__((ext_vector_type(8)));
typedef _Float16 half4 __attribute__((ext_vector_type(4)));
typedef float floatx16 __attribute__((ext_vector_type(16)));

#define MFMA_F16(A, B, C) __builtin_amdgcn_mfma_f32_32x32x16_f16(A, B, C, 0, 0, 0)

constexpr int Bn = 4;     // batch
constexpr int Cc = 256;   // channels
constexpr int Cq = 32;    // C/8
constexpr int Nn = 4096;  // tokens (64*64)
constexpr float LOG2E = 1.44269504088896340736f;

// Layouts (all chosen so every per-iter fragment load is lane-dense):
//   K4[b][cidx=0..3][n][8]           : K B-fragment chunks
//   V8[b][nb=n>>3][c][8]             : V A-fragment chunks
//   W4[(c>>3)*32 + o][8] (per tile)  : W A-fragment chunks (k_proj)

__device__ inline floatx16 zero16() {
  floatx16 z;
#pragma unroll
  for (int i = 0; i < 16; ++i) z[i] = 0.f;
  return z;
}

// ---------------------------------------------------------------------------
// Kernel 0: W fp32 -> f16 fragment-tiled W4 (Wf scaled by log2e).
// ---------------------------------------------------------------------------
__global__ __launch_bounds__(256) void k_wconv(
    const float* __restrict__ Wf, const float* __restrict__ Wg,
    const float* __restrict__ Wh, _Float16* __restrict__ Wf4,
    _Float16* __restrict__ Wg4, _Float16* __restrict__ Wh4) {
  int e = (blockIdx.x * 256 + threadIdx.x) * 4;
  const float* src;
  _Float16* dst;
  float sc = 1.f;
  if (e < 8192) {
    int o = e >> 8, c = e & 255;
    src = Wf + e;
    dst = Wf4 + (((c >> 3) * 32 + o) << 3) + (c & 7);
    sc = LOG2E;
  } else if (e < 16384) {
    int e0 = e - 8192;
    int o = e0 >> 8, c = e0 & 255;
    src = Wg + e0;
    dst = Wg4 + (((c >> 3) * 32 + o) << 3) + (c & 7);
  } else {
    int e0 = e - 16384;
    int o = e0 >> 8, c = e0 & 255;
    int ot = o >> 5, orr = o & 31;
    src = Wh + e0;
    dst = Wh4 + ot * 8192 + (((c >> 3) * 32 + orr) << 3) + (c & 7);
  }
  float4 v = *(const float4*)src;
  half4 o4;
  o4[0] = (_Float16)(v.x * sc); o4[1] = (_Float16)(v.y * sc);
  o4[2] = (_Float16)(v.z * sc); o4[3] = (_Float16)(v.w * sc);
  *(half4*)dst = o4;  // 8B-aligned: (c&7) in {0,4}
}

// ---------------------------------------------------------------------------
// Kernel 1: projections straight from x[b][c][n]; W4 dense A-fragments.
// Q token-major; K -> K4; V -> V8.
// ---------------------------------------------------------------------------
__global__ __launch_bounds__(256) void k_proj(
    const float* __restrict__ x,
    const _Float16* __restrict__ Wf4, const float* __restrict__ bf,
    const _Float16* __restrict__ Wg4, const float* __restrict__ bg,
    const _Float16* __restrict__ Wh4, const float* __restrict__ bh,
    _Float16* __restrict__ Q, _Float16* __restrict__ K4,
    _Float16* __restrict__ V8) {
  int tid = threadIdx.x;
  int w = tid >> 6, lane = tid & 63;
  int ml = lane & 31, h = lane >> 5;
  int b = blockIdx.x >> 7, nt = blockIdx.x & 127;
  int n0 = nt * 32;
  const float* xb = x + (size_t)b * Cc * Nn + n0 + ml;

  for (int t = w; t < 10; t += 4) {
    const _Float16* W4;
    const float* bias;
    float bscale = 1.f;
    int o0 = 0;
    if (t == 0) { W4 = Wf4; bias = bf; bscale = LOG2E; }
    else if (t == 1) { W4 = Wg4; bias = bg; }
    else { W4 = Wh4 + (size_t)(t - 2) * 8192; bias = bh + (t - 2) * 32; o0 = (t - 2) * 32; }

    floatx16 acc = zero16();
#pragma unroll
    for (int kc = 0; kc < 16; ++kc) {
      // dense A-fragment: chunk = kc*2+h, row = ml
      half8 a = *(const half8*)(W4 + ((((kc * 2 + h) * 32) + ml) << 3));
      const float* xp = xb + (size_t)(kc * 16 + h * 8) * Nn;
      half8 bfr;
#pragma unroll
      for (int j = 0; j < 8; ++j) bfr[j] = (_Float16)xp[(size_t)j * Nn];
      acc = MFMA_F16(a, bfr, acc);
    }

    if (t == 0) {
      _Float16* op = Q + ((size_t)b * Nn + n0 + ml) * Cq;
#pragma unroll
      for (int qd = 0; qd < 4; ++qd) {
        float4 bq = *(const float4*)(bias + 8 * qd + 4 * h);
        const float* bqp = (const float*)&bq;
#pragma unroll
        for (int i = 0; i < 4; ++i) {
          int crow = i + 8 * qd + 4 * h;
          op[crow] = (_Float16)(acc[4 * qd + i] + bqp[i] * bscale);
        }
      }
    } else if (t == 1) {
#pragma unroll
      for (int qd = 0; qd < 4; ++qd) {
        float4 bq = *(const float4*)(bias + 8 * qd + 4 * h);
        const float* bqp = (const float*)&bq;
#pragma unroll
        for (int i = 0; i < 4; ++i) {
          int crow = i + 8 * qd + 4 * h;
          K4[(((size_t)b * 4 + (crow >> 3)) * Nn + n0 + ml) * 8 + (crow & 7)] =
              (_Float16)(acc[4 * qd + i] + bqp[i]);
        }
      }
    } else {
      size_t nb = (size_t)((n0 + ml) >> 3);
      _Float16* op = V8 + (((size_t)b * 512 + nb) * 256) * 8 + (ml & 7);
#pragma unroll
      for (int qd = 0; qd < 4; ++qd) {
        float4 bq = *(const float4*)(bias + 8 * qd + 4 * h);
        const float* bqp = (const float*)&bq;
#pragma unroll
        for (int i = 0; i < 4; ++i) {
          int crow = i + 8 * qd + 4 * h;
          op[(size_t)(o0 + crow) * 8] = (_Float16)(acc[4 * qd + i] + bqp[i]);
        }
      }
    }
  }
}

// ---------------------------------------------------------------------------
// Kernel 2: pass-1 row max (log2-domain), coalesced K4.
// MFMA bitwise identical to k_attn's S -> exp2(s-M) <= 1 exactly.
// ---------------------------------------------------------------------------
__global__ __launch_bounds__(512) void k_rowmax(const _Float16* __restrict__ Q,
                                                const _Float16* __restrict__ K4,
                                                float* __restrict__ M) {
  __shared__ float red[8][32];
  int tid = threadIdx.x, w = tid >> 6, lane = tid & 63;
  int ml = lane & 31, h = lane >> 5;
  int b = blockIdx.x >> 7, mt = blockIdx.x & 127;
  int m0 = mt * 32;
  const _Float16* qp = Q + ((size_t)b * Nn + m0 + ml) * Cq + h * 8;
  half8 qb0 = *(const half8*)(qp);
  half8 qb1 = *(const half8*)(qp + 16);
  const _Float16* kp0 = K4 + (((size_t)b * 4 + h) * Nn + w * 512 + ml) * 8;
  const _Float16* kp1 = K4 + (((size_t)b * 4 + 2 + h) * Nn + w * 512 + ml) * 8;
  float mx = -3.0e38f;
  for (int t = 0; t < 16; ++t) {
    floatx16 s = zero16();
    half8 k0 = *(const half8*)(kp0 + (size_t)t * 32 * 8);
    half8 k1 = *(const half8*)(kp1 + (size_t)t * 32 * 8);
    s = MFMA_F16(k0, qb0, s);
    s = MFMA_F16(k1, qb1, s);
#pragma unroll
    for (int i = 0; i < 16; ++i) mx = fmaxf(mx, s[i]);
  }
  mx = fmaxf(mx, __shfl_xor(mx, 32, 64));
  if (h == 0) red[w][ml] = mx;
  __syncthreads();
  if (tid < 32) {
    float m2 = red[0][tid];
#pragma unroll
    for (int i = 1; i < 8; ++i) m2 = fmaxf(m2, red[i][tid]);
    M[(size_t)b * Nn + m0 + tid] = m2;
  }
}

// ---------------------------------------------------------------------------
// Kernel 3: pass-2 attention v9 = v8 structure at NC=4 (4 barrier groups/CU).
// Grid: NC x 4 x 64 blocks of 512 thr (8 waves); LDS 33 KB -> 4 blocks/CU.
// S phase: wave (msub,nq) -> 32m x 32n subtile of 64m x 128n P tile,
// exp2 -> LDS (XOR 16B-chunk swizzle; write b64, read b128 conflict-free).
// PV: wave w -> c0=w*32, both m-halves: per kc 1 coalesced V b128 +
// 2 P b128 + 2 MFMA. Single barrier/iter, double-buffered P.
// Unnormalized f16 O-partials + fp32 l-partials; k_fin combines.
// ---------------------------------------------------------------------------
__global__ __launch_bounds__(512, 4) void k_attn(
    const _Float16* __restrict__ Q, const _Float16* __restrict__ K4,
    const _Float16* __restrict__ V8, const float* __restrict__ M,
    _Float16* __restrict__ Opart, float* __restrict__ lpart, int nspan) {
  __shared__ _Float16 P[2 * 64 * 128];
  __shared__ float lred[8][32];
  int tid = threadIdx.x, w = tid >> 6, lane = tid & 63;
  int ml = lane & 31, h = lane >> 5;
  int msub = w & 1, nq = w >> 1;
  int bx = blockIdx.x;
  int mt = bx & 63, b = (bx >> 6) & 3, nc = bx >> 8;
  int m0 = mt * 64;
  int nbase0 = nc * nspan;
  int sw = ml & 15;

  const _Float16* qp = Q + ((size_t)b * Nn + m0 + msub * 32 + ml) * Cq + h * 8;
  half8 qb0 = *(const half8*)(qp);
  half8 qb1 = *(const half8*)(qp + 16);
  float Mv = M[(size_t)b * Nn + m0 + msub * 32 + ml];
  float lacc = 0.f;

  const _Float16* k4b0 =
      K4 + (((size_t)b * 4 + h) * Nn + nbase0 + nq * 32 + ml) * 8;
  const _Float16* k4b1 =
      K4 + (((size_t)b * 4 + 2 + h) * Nn + nbase0 + nq * 32 + ml) * 8;

  int c0 = w * 32;
  const _Float16* v8b =
      V8 + (((size_t)b * 512 + (nbase0 >> 3)) * 256 + c0 + ml) * 8;

  floatx16 o0 = zero16(), o1 = zero16();
  int iters = nspan >> 7;
  _Float16* pwbase = &P[(msub * 32 + ml) * 128];
  const _Float16* pr0 = &P[ml * 128];
  const _Float16* pr1 = &P[(32 + ml) * 128];

  for (int it = 0; it < iters; ++it) {
    int bufo = (it & 1) * (64 * 128);
    // ---- S phase ----
    {
      floatx16 s = zero16();
      half8 k0 = *(const half8*)(k4b0 + (size_t)it * 128 * 8);
      half8 k1 = *(const half8*)(k4b1 + (size_t)it * 128 * 8);
      s = MFMA_F16(k0, qb0, s);
      s = MFMA_F16(k1, qb1, s);
      _Float16* pw = pwbase + bufo;
#pragma unroll
      for (int q = 0; q < 4; ++q) {
        float p0 = exp2f(s[4 * q + 0] - Mv);
        float p1 = exp2f(s[4 * q + 1] - Mv);
        float p2 = exp2f(s[4 * q + 2] - Mv);
        float p3 = exp2f(s[4 * q + 3] - Mv);
        lacc += (p0 + p1) + (p2 + p3);
        half4 pk;
        pk[0] = (_Float16)p0; pk[1] = (_Float16)p1;
        pk[2] = (_Float16)p2; pk[3] = (_Float16)p3;
        *(half4*)(pw + ((nq * 4 + q) ^ sw) * 8 + 4 * h) = pk;  // ds_write_b64
      }
    }
    __syncthreads();
    // ---- PV phase: coalesced V + swizzled P reads ----
    {
      const _Float16* vp = v8b + (size_t)it * 16 * 2048;  // 2048 = 256*8
      const _Float16* p0b = pr0 + bufo;
      const _Float16* p1b = pr1 + bufo;
#pragma unroll
      for (int kc = 0; kc < 8; ++kc) {
        half8 vf = *(const half8*)(vp + (size_t)(kc * 2 + h) * 2048);
        int chunk = (kc * 2 + h) ^ sw;
        half8 pb0 = *(const half8*)(p0b + chunk * 8);  // ds_read_b128
        half8 pb1 = *(const half8*)(p1b + chunk * 8);
        o0 = MFMA_F16(vf, pb0, o0);
        o1 = MFMA_F16(vf, pb1, o1);
      }
    }
  }

  // ---- l reduction ----
  lacc += __shfl_xor(lacc, 32, 64);
  if (h == 0) lred[w][ml] = lacc;
  __syncthreads();
  if (w < 2 && h == 0) {
    float lsum = lred[w][ml] + lred[w + 2][ml] + lred[w + 4][ml] + lred[w + 6][ml];
    lpart[((size_t)nc * Bn + b) * Nn + m0 + w * 32 + ml] = lsum;
  }

  // ---- store unnormalized O^T partials (f16) ----
  _Float16* op0 = Opart + ((size_t)((size_t)nc * Bn + b) * Cc) * Nn + (m0 + ml);
#pragma unroll
  for (int r = 0; r < 16; ++r) {
    int c = c0 + (r & 3) + 8 * (r >> 2) + 4 * h;
    op0[(size_t)c * Nn] = (_Float16)o0[r];
    op0[(size_t)c * Nn + 32] = (_Float16)o1[r];
  }
}

// ---------------------------------------------------------------------------
// Kernel 4: combine chunk partials: out = gamma*(sum O)/(sum l) + input
// ---------------------------------------------------------------------------
__global__ __launch_bounds__(256) void k_fin(const _Float16* __restrict__ Op,
                                             const float* __restrict__ lp,
                                             const float* __restrict__ inp,
                                             const float* __restrict__ gamma,
                                             float* __restrict__ out, int NC) {
  int i4 = (blockIdx.x * 256 + threadIdx.x) * 4;
  int m = i4 & (Nn - 1);
  int bc = i4 >> 12;        // b*256 + c
  int b = bc >> 8;
  float ax = 0.f, ay = 0.f, az = 0.f, aw = 0.f;
  float lx = 0.f, ly = 0.f, lz = 0.f, lw = 0.f;
  for (int nc = 0; nc < NC; ++nc) {
    half4 o = *(const half4*)(Op + ((size_t)nc * Bn * Cc + bc) * Nn + m);
    float4 lv = *(const float4*)(lp + ((size_t)nc * Bn + b) * Nn + m);
    ax += (float)o[0]; ay += (float)o[1]; az += (float)o[2]; aw += (float)o[3];
    lx += lv.x; ly += lv.y; lz += lv.z; lw += lv.w;
  }
  float g = gamma[0];
  float4 xi = *(const float4*)(inp + (size_t)i4);
  float4 r;
  r.x = g * ax / lx + xi.x;
  r.y = g * ay / ly + xi.y;
  r.z = g * az / lz + xi.z;
  r.w = g * aw / lw + xi.w;
  *(float4*)(out + (size_t)i4) = r;
}

// ---------------------------------------------------------------------------
extern "C" void kernel_launch(void* const* d_in, const int* in_sizes, int n_in,
                              void* d_out, int out_size, void* d_ws,
                              size_t ws_size, hipStream_t stream) {
  const float* x = (const float*)d_in[0];
  const float* Wf = (const float*)d_in[1];
  const float* bf = (const float*)d_in[2];
  const float* Wg = (const float*)d_in[3];
  const float* bg = (const float*)d_in[4];
  const float* Wh = (const float*)d_in[5];
  const float* bh = (const float*)d_in[6];
  const float* gamma = (const float*)d_in[7];
  float* out = (float*)d_out;

  char* ws = (char*)d_ws;
  // Layout (bytes):
  //   Q      [0,        1048576)
  //   K4     [1048576,  2097152)
  //   V8     [2097152, 10485760)
  //   M      [10485760, 10551296)
  //   Wf4    [10551296, 10567680)
  //   Wg4    [10567680, 10584064)
  //   Wh4    [10584064, 10715136)
  //   lpart  [10715136, 10977280)   (up to 4 chunks x 64 KB)
  //   Opart  [10977280, 10977280 + NC*8388608)
  _Float16* Q  = (_Float16*)(ws);
  _Float16* K4 = (_Float16*)(ws + 1048576);
  _Float16* V8 = (_Float16*)(ws + 2097152);
  float*    M  = (float*)   (ws + 10485760);
  _Float16* Wf4 = (_Float16*)(ws + 10551296);
  _Float16* Wg4 = (_Float16*)(ws + 10567680);
  _Float16* Wh4 = (_Float16*)(ws + 10584064);
  float*    lpart = (float*)(ws + 10715136);
  _Float16* Opart = (_Float16*)(ws + 10977280);

  size_t base = 10977280u;
  int NC = 1;
  if (ws_size >= base + 4u * 8388608u) NC = 4;
  else if (ws_size >= base + 2u * 8388608u) NC = 2;
  int nspan = Nn / NC;

  k_wconv<<<dim3(80), dim3(256), 0, stream>>>(Wf, Wg, Wh, Wf4, Wg4, Wh4);
  k_proj<<<dim3(512), dim3(256), 0, stream>>>(x, Wf4, bf, Wg4, bg, Wh4, bh, Q, K4, V8);
  k_rowmax<<<dim3(512), dim3(512), 0, stream>>>(Q, K4, M);
  k_attn<<<dim3(NC * 256), dim3(512), 0, stream>>>(Q, K4, V8, M, Opart, lpart, nspan);
  k_fin<<<dim3(4096), dim3(256), 0, stream>>>(Opart, lpart, x, gamma, out, NC);
}